// Round 14
// baseline (112.958 us; speedup 1.0000x reference)
//
#include <hip/hip_runtime.h>
#include <math.h>

// x: (8,16,512,64) fp32; flat = [wk | wq], each (64,4). Output: int32 top-12 idx.
constexpr int kDIn  = 64;
constexpr int kN    = 512;
constexpr int kTopK = 12;
constexpr int kNBt  = 128;          // 8*16
constexpr int kS    = 4;            // row-slices per tile
constexpr int kRows = kN / kS;      // 128 rows per block
// exp(SCALE*h) = exp2(CEXP*h); SCALE = 0.125; CEXP = SCALE*log2(e)
#define CEXP 0.18033688f
#define EXP2(v) __builtin_amdgcn_exp2f(v)
#define LOG2F(v) __builtin_amdgcn_logf(v)       // v_log_f32 = log base 2
// NUMERIC INVARIANT (R3/R5): every exp2 argument <= 0. Online rowstats keeps a
// running EXACT max at chunk granularity: rescale factor <= 1, slice l in
// [1,512]. No denormal, no inf, immune to FTZ.
// LDS BUDGET (R9/R11): ds_read_b128 ~12cyc/instr/CU; weights stay in SGPRs.
// LAUNCH BUDGET (R7/R14): 2-kernel pipeline pays ~7us of gap; last-block
// fusion (threadfence + device atomic, no spin) folds topk into KA.

#define DOT4(k, q)        fmaf((k).x,(q).x, fmaf((k).y,(q).y, fmaf((k).z,(q).z, (k).w*(q).w)))
#define DOT4A(k, q, add)  fmaf((k).x,(q).x, fmaf((k).y,(q).y, fmaf((k).z,(q).z, fmaf((k).w,(q).w,(add)))))

// ws layout: apart [128][16][512] floats (4 MB) + counters [128] int
constexpr size_t kApFloats = (size_t)kNBt * 16 * kN;
constexpr size_t kWsBytes  = kApFloats * 4 + kNBt * 4;

// ============ KA: fused projection + online rowstats + colsum + topk ============
// grid 512, block 512, 2 blocks/CU. XCD swizzle keeps 4 same-tile blocks on one
// XCD (x tile L2-resident). Last block per tile runs the top-12 inline.
__global__ __launch_bounds__(512, 4) void fused_attn_kernel(
    const float* __restrict__ x, const float* __restrict__ flat,
    float* __restrict__ apart, int* __restrict__ counters,
    int* __restrict__ out)
{
  __shared__ float4 Qs[kN];                    // unscaled Q (8 KB)
  __shared__ float4 Ks[kRows];                 // CEXP-scaled K slice (2 KB)
  __shared__ float2 Pp[16 * kRows];            // (m,l) per (j-slice,row) (16 KB)
  __shared__ __align__(16) float Cs[kRows];    // c_i = m_i + log2(l_i)
  __shared__ int lastArr;

  const int tid  = threadIdx.x;
  const int p    = blockIdx.x;
  const int xcd  = p & 7;
  const int s    = (p >> 3) & 3;
  const int tile = ((p >> 5) << 3) | xcd;

  // ---- phase 1: thread t projects row t; 16 x-loads prefetched; weights via
  // uniform s_load (SGPR operands), zero LDS traffic.
  {
    const float4* fw  = reinterpret_cast<const float4*>(flat);   // [128] uniform
    const float4* xr4 = reinterpret_cast<const float4*>(x + ((size_t)tile * kN + tid) * kDIn);
    float4 xv[16];
#pragma unroll
    for (int i = 0; i < 16; ++i) xv[i] = xr4[i];

    float q0=0.f,q1=0.f,q2=0.f,q3=0.f;
    if ((tid >> 7) == s) {                     // wave-uniform branch
      float k0=0.f,k1=0.f,k2=0.f,k3=0.f;
#pragma unroll
      for (int cc = 0; cc < 16; ++cc) {
#pragma unroll
        for (int u = 0; u < 4; ++u) {
          float v = (u==0)?xv[cc].x:(u==1)?xv[cc].y:(u==2)?xv[cc].z:xv[cc].w;
          float4 a = fw[cc*4+u];
          float4 b = fw[64 + cc*4+u];
          k0 = fmaf(v, a.x, k0); k1 = fmaf(v, a.y, k1);
          k2 = fmaf(v, a.z, k2); k3 = fmaf(v, a.w, k3);
          q0 = fmaf(v, b.x, q0); q1 = fmaf(v, b.y, q1);
          q2 = fmaf(v, b.z, q2); q3 = fmaf(v, b.w, q3);
        }
      }
      Ks[tid & 127] = make_float4(CEXP*k0, CEXP*k1, CEXP*k2, CEXP*k3);
    } else {
#pragma unroll
      for (int cc = 0; cc < 16; ++cc) {
#pragma unroll
        for (int u = 0; u < 4; ++u) {
          float v = (u==0)?xv[cc].x:(u==1)?xv[cc].y:(u==2)?xv[cc].z:xv[cc].w;
          float4 b = fw[64 + cc*4+u];
          q0 = fmaf(v, b.x, q0); q1 = fmaf(v, b.y, q1);
          q2 = fmaf(v, b.z, q2); q3 = fmaf(v, b.w, q3);
        }
      }
    }
    Qs[tid] = make_float4(q0, q1, q2, q3);
  }
  __syncthreads();

  // ---- phase 2: ONLINE rowstats, register-tiled (R13 proven) ----
  {
    const int quad  = tid & 31;
    const int slice = tid >> 5;
    const float4 k0 = Ks[quad*4+0], k1 = Ks[quad*4+1];
    const float4 k2 = Ks[quad*4+2], k3 = Ks[quad*4+3];
    const float4* qb = &Qs[slice << 5];

    float m0=-INFINITY, m1=-INFINITY, m2=-INFINITY, m3=-INFINITY;
    float l0=0.f, l1=0.f, l2=0.f, l3=0.f;
#pragma unroll
    for (int c = 0; c < 32; c += 8) {
      float4 qv0 = qb[c+0], qv1 = qb[c+1], qv2 = qb[c+2], qv3 = qb[c+3];
      float4 qv4 = qb[c+4], qv5 = qb[c+5], qv6 = qb[c+6], qv7 = qb[c+7];
#define ROW_ONLINE(KR, MR, LR)                                                 \
      {                                                                        \
        float d0 = DOT4(KR, qv0), d1 = DOT4(KR, qv1);                          \
        float d2 = DOT4(KR, qv2), d3 = DOT4(KR, qv3);                          \
        float d4 = DOT4(KR, qv4), d5 = DOT4(KR, qv5);                          \
        float d6 = DOT4(KR, qv6), d7 = DOT4(KR, qv7);                          \
        float cm = fmaxf(fmaxf(fmaxf(d0,d1), fmaxf(d2,d3)),                    \
                         fmaxf(fmaxf(d4,d5), fmaxf(d6,d7)));                   \
        if (cm > MR) { LR *= EXP2(MR - cm); MR = cm; }                         \
        LR += ((EXP2(d0-MR) + EXP2(d1-MR)) + (EXP2(d2-MR) + EXP2(d3-MR)))      \
            + ((EXP2(d4-MR) + EXP2(d5-MR)) + (EXP2(d6-MR) + EXP2(d7-MR)));     \
      }
      ROW_ONLINE(k0, m0, l0)
      ROW_ONLINE(k1, m1, l1)
      ROW_ONLINE(k2, m2, l2)
      ROW_ONLINE(k3, m3, l3)
#undef ROW_ONLINE
    }
    float4* pp4 = reinterpret_cast<float4*>(&Pp[slice * kRows + quad*4]);
    pp4[0] = make_float4(m0, l0, m1, l1);
    pp4[1] = make_float4(m2, l2, m3, l3);
  }
  __syncthreads();

  // ---- merge 16 j-slice partials per row (exact max, scaled sums) ----
  if (tid < kRows) {
    float m = -INFINITY;
    float2 pr[16];
#pragma unroll
    for (int sl = 0; sl < 16; ++sl) {
      pr[sl] = Pp[sl * kRows + tid];
      m = fmaxf(m, pr[sl].x);
    }
    float l = 0.f;
#pragma unroll
    for (int sl = 0; sl < 16; ++sl) l += pr[sl].y * EXP2(pr[sl].x - m);
    Cs[tid] = m + LOG2F(l);            // l in [1,512]
  }
  __syncthreads();

  // ---- phase 3: colsum, register-tiled (R10/R12 proven) ----
  {
    const int cq = tid & 127;
    const int rs = tid >> 7;
    const float4 q0 = Qs[cq*4+0], q1 = Qs[cq*4+1];
    const float4 q2 = Qs[cq*4+2], q3 = Qs[cq*4+3];
    const float4* kb = &Ks[rs << 5];
    const float4* cb = reinterpret_cast<const float4*>(&Cs[rs << 5]);

    float a0=0.f, a1=0.f, a2=0.f, a3=0.f;
#pragma unroll 2
    for (int ii = 0; ii < 8; ++ii) {
      float4 cc = cb[ii];
      float4 ka = kb[ii*4+0], kb_ = kb[ii*4+1], kc = kb[ii*4+2], kd = kb[ii*4+3];
      a0 += EXP2(DOT4A(q0, ka, -cc.x));  a1 += EXP2(DOT4A(q1, ka, -cc.x));
      a2 += EXP2(DOT4A(q2, ka, -cc.x));  a3 += EXP2(DOT4A(q3, ka, -cc.x));
      a0 += EXP2(DOT4A(q0, kb_, -cc.y)); a1 += EXP2(DOT4A(q1, kb_, -cc.y));
      a2 += EXP2(DOT4A(q2, kb_, -cc.y)); a3 += EXP2(DOT4A(q3, kb_, -cc.y));
      a0 += EXP2(DOT4A(q0, kc, -cc.z));  a1 += EXP2(DOT4A(q1, kc, -cc.z));
      a2 += EXP2(DOT4A(q2, kc, -cc.z));  a3 += EXP2(DOT4A(q3, kc, -cc.z));
      a0 += EXP2(DOT4A(q0, kd, -cc.w));  a1 += EXP2(DOT4A(q1, kd, -cc.w));
      a2 += EXP2(DOT4A(q2, kd, -cc.w));  a3 += EXP2(DOT4A(q3, kd, -cc.w));
    }
    reinterpret_cast<float4*>(apart + ((size_t)(tile*4 + s) * 4 + rs) * kN)[cq] =
        make_float4(a0, a1, a2, a3);
  }

  // ---- last-block fusion: 4th arriver per tile runs the top-12 inline ----
  __threadfence();                              // release apart writes (device)
  if (tid == 0) {
    int old = atomicAdd(&counters[tile], 1);    // device-scope
    lastArr = (old == 3);
  }
  __syncthreads();

  if (lastArr && tid < 64) {
    __threadfence();                            // acquire other blocks' writes
    const int lane = tid;
    const float* P = apart + (size_t)tile * 16 * kN;

    float v[8];
    {
      float4 acc0 = make_float4(0.f,0.f,0.f,0.f);
      float4 acc1 = make_float4(0.f,0.f,0.f,0.f);
#pragma unroll
      for (int sl = 0; sl < 16; ++sl) {
        const float4* Ps = reinterpret_cast<const float4*>(P + sl * kN);
        float4 u0 = Ps[lane*2], u1 = Ps[lane*2+1];
        acc0.x += u0.x; acc0.y += u0.y; acc0.z += u0.z; acc0.w += u0.w;
        acc1.x += u1.x; acc1.y += u1.y; acc1.z += u1.z; acc1.w += u1.w;
      }
      v[0]=acc0.x; v[1]=acc0.y; v[2]=acc0.z; v[3]=acc0.w;
      v[4]=acc1.x; v[5]=acc1.y; v[6]=acc1.z; v[7]=acc1.w;
    }

    for (int rnd = 0; rnd < kTopK; ++rnd) {
      float bv = v[0];
      int   bi = lane * 8;
#pragma unroll
      for (int r = 1; r < 8; ++r) {
        if (v[r] > bv) { bv = v[r]; bi = lane * 8 + r; }
      }
#pragma unroll
      for (int off = 32; off >= 1; off >>= 1) {
        float ov = __shfl_xor(bv, off);
        int   oi = __shfl_xor(bi, off);
        if (ov > bv || (ov == bv && oi < bi)) { bv = ov; bi = oi; }
      }
      if (lane == 0) out[tile * kTopK + rnd] = bi;
#pragma unroll
      for (int r = 0; r < 8; ++r) {
        if (lane * 8 + r == bi) v[r] = -INFINITY;
      }
    }
  }
}

// ============ fallback: round-1 single kernel (unexpected shape / tiny ws) ============
__global__ __launch_bounds__(512, 1) void sparse_attn_topk_fallback(
    const float* __restrict__ x, const float* __restrict__ flat, int* __restrict__ out)
{
  __shared__ float4 wk4[kDIn];
  __shared__ float4 wq4[kDIn];
  __shared__ float4 Ks[kN];
  __shared__ float4 Qs[kN];
  __shared__ float  Ms[kN];
  __shared__ float  Rl[kN];
  __shared__ float  As[kN];

  const int tid = threadIdx.x;
  const int bt  = blockIdx.x;

  if (tid < 64)       wk4[tid]      = reinterpret_cast<const float4*>(flat)[tid];
  else if (tid < 128) wq4[tid - 64] = reinterpret_cast<const float4*>(flat)[tid];
  __syncthreads();

  const float* xr = x + ((size_t)bt * kN + tid) * kDIn;
  float k0=0.f,k1=0.f,k2=0.f,k3=0.f, q0=0.f,q1=0.f,q2=0.f,q3=0.f;
#pragma unroll
  for (int c = 0; c < kDIn; ++c) {
    float xv = xr[c];
    float4 a = wk4[c];
    float4 b = wq4[c];
    k0 = fmaf(xv, a.x, k0); k1 = fmaf(xv, a.y, k1);
    k2 = fmaf(xv, a.z, k2); k3 = fmaf(xv, a.w, k3);
    q0 = fmaf(xv, b.x, q0); q1 = fmaf(xv, b.y, q1);
    q2 = fmaf(xv, b.z, q2); q3 = fmaf(xv, b.w, q3);
  }
  Ks[tid] = make_float4(k0, k1, k2, k3);
  Qs[tid] = make_float4(q0, q1, q2, q3);
  __syncthreads();

  float m = -INFINITY;
#pragma unroll 8
  for (int j = 0; j < kN; ++j) {
    float4 qj = Qs[j];
    float h = fmaf(k0, qj.x, fmaf(k1, qj.y, fmaf(k2, qj.z, k3 * qj.w)));
    m = fmaxf(m, h);
  }
  float l = 0.f;
#pragma unroll 8
  for (int j = 0; j < kN; ++j) {
    float4 qj = Qs[j];
    float h = fmaf(k0, qj.x, fmaf(k1, qj.y, fmaf(k2, qj.z, k3 * qj.w)));
    l += exp2f(CEXP * (h - m));
  }
  Ms[tid] = m;
  Rl[tid] = 1.0f / l;
  __syncthreads();

  float acc = 0.f;
#pragma unroll 8
  for (int i = 0; i < kN; ++i) {
    float4 ki = Ks[i];
    float h = fmaf(q0, ki.x, fmaf(q1, ki.y, fmaf(q2, ki.z, q3 * ki.w)));
    acc += exp2f(CEXP * (h - Ms[i])) * Rl[i];
  }
  As[tid] = acc;
  __syncthreads();

  if (tid < 64) {
    float v[8];
#pragma unroll
    for (int r = 0; r < 8; ++r) v[r] = As[tid * 8 + r];
    for (int rnd = 0; rnd < kTopK; ++rnd) {
      float bv = v[0];
      int   bi = tid * 8;
#pragma unroll
      for (int r = 1; r < 8; ++r)
        if (v[r] > bv) { bv = v[r]; bi = tid * 8 + r; }
#pragma unroll
      for (int off = 32; off >= 1; off >>= 1) {
        float ov = __shfl_xor(bv, off);
        int   oi = __shfl_xor(bi, off);
        if (ov > bv || (ov == bv && oi < bi)) { bv = ov; bi = oi; }
      }
      if (tid == 0) out[bt * kTopK + rnd] = bi;
#pragma unroll
      for (int r = 0; r < 8; ++r)
        if (tid * 8 + r == bi) v[r] = -INFINITY;
    }
  }
}

extern "C" void kernel_launch(void* const* d_in, const int* in_sizes, int n_in,
                              void* d_out, int out_size, void* d_ws, size_t ws_size,
                              hipStream_t stream) {
  const float* x    = (const float*)d_in[0];
  const float* flat = (const float*)d_in[1];
  int* out = (int*)d_out;
  const int n_bt = in_sizes[0] / (kN * kDIn);

  if (n_bt != kNBt || ws_size < kWsBytes) {
    sparse_attn_topk_fallback<<<n_bt, kN, 0, stream>>>(x, flat, out);
    return;
  }
  float* apart   = (float*)d_ws;
  int*   counters = (int*)((char*)d_ws + kApFloats * 4);

  // counters must start at 0 each call (ws is poisoned to 0xAA once; graph
  // replays this memset node every iteration). 512 B, ~negligible.
  hipMemsetAsync(counters, 0, kNBt * sizeof(int), stream);
  fused_attn_kernel<<<kNBt * kS, 512, 0, stream>>>(x, flat, apart, counters, out);
}

// Round 15
// 37.344 us; speedup vs baseline: 3.0248x; 3.0248x over previous
//
#include <hip/hip_runtime.h>
#include <math.h>

// x: (8,16,512,64) fp32; flat = [wk | wq], each (64,4). Output: int32 top-12 idx.
constexpr int kDIn  = 64;
constexpr int kN    = 512;
constexpr int kTopK = 12;
constexpr int kNBt  = 128;          // 8*16
constexpr int kS    = 4;            // row-slices per tile
constexpr int kRows = kN / kS;      // 128 rows per block
// exp(SCALE*h) = exp2(CEXP*h); SCALE = 0.125; CEXP = SCALE*log2(e)
#define CEXP 0.18033688f
#define EXP2(v) __builtin_amdgcn_exp2f(v)
#define LOG2F(v) __builtin_amdgcn_logf(v)       // v_log_f32 = log base 2
// NUMERIC INVARIANT (R3/R5): every exp2 argument <= 0. Online rowstats keeps a
// running EXACT max; shfl merge rescales with factors <= 1. l in [1,512].
// No denormal, no inf, immune to FTZ.
// SYNC BUDGET (R11/R14): grid.sync() and __threadfence() cost 70-90us on this
// chip (L2 writeback across XCDs) -- two-kernel pipeline is cheaper.
// LDS BUDGET (R9/R11): ds_read_b128 ~12cyc/instr/CU; weights in SGPRs.

#define DOT4(k, q)        fmaf((k).x,(q).x, fmaf((k).y,(q).y, fmaf((k).z,(q).z, (k).w*(q).w)))
#define DOT4A(k, q, add)  fmaf((k).x,(q).x, fmaf((k).y,(q).y, fmaf((k).z,(q).z, fmaf((k).w,(q).w,(add)))))

// padded Q index: +1 float4 per 32 rows (breaks 512B-stride bank aliasing)
#define QIDX(j) ((j) + ((j) >> 5))

// ws: apart [128 tiles][16 slices][512 cols] floats = 4 MB
constexpr size_t kWsFloats = (size_t)kNBt * 16 * kN;

// ============ KA: fused projection + online rowstats (shfl-merged) + colsum ============
// grid 512, block 512, 3 blocks/CU. XCD swizzle keeps 4 same-tile blocks on one
// XCD (x tile L2-resident).
__global__ __launch_bounds__(512, 6) void fused_attn_kernel(
    const float* __restrict__ x, const float* __restrict__ flat,
    float* __restrict__ apart)
{
  __shared__ float4 Qs[kN + 16];               // padded unscaled Q (8.25 KB)
  __shared__ float4 Ks[kRows];                 // CEXP-scaled K slice (2 KB)
  __shared__ __align__(16) float Cs[kRows];    // c_i = m_i + log2(l_i)

  const int tid  = threadIdx.x;
  const int p    = blockIdx.x;
  const int xcd  = p & 7;
  const int s    = (p >> 3) & 3;
  const int tile = ((p >> 5) << 3) | xcd;

  // ---- phase 1: thread t projects row t; x-loads prefetched; weights via
  // uniform s_load (SGPR operands), zero LDS traffic. (R12/R13 proven)
  {
    const float4* fw  = reinterpret_cast<const float4*>(flat);   // [128] uniform
    const float4* xr4 = reinterpret_cast<const float4*>(x + ((size_t)tile * kN + tid) * kDIn);
    float4 xv[16];
#pragma unroll
    for (int i = 0; i < 16; ++i) xv[i] = xr4[i];

    float q0=0.f,q1=0.f,q2=0.f,q3=0.f;
    if ((tid >> 7) == s) {                     // wave-uniform branch
      float k0=0.f,k1=0.f,k2=0.f,k3=0.f;
#pragma unroll
      for (int cc = 0; cc < 16; ++cc) {
#pragma unroll
        for (int u = 0; u < 4; ++u) {
          float v = (u==0)?xv[cc].x:(u==1)?xv[cc].y:(u==2)?xv[cc].z:xv[cc].w;
          float4 a = fw[cc*4+u];
          float4 b = fw[64 + cc*4+u];
          k0 = fmaf(v, a.x, k0); k1 = fmaf(v, a.y, k1);
          k2 = fmaf(v, a.z, k2); k3 = fmaf(v, a.w, k3);
          q0 = fmaf(v, b.x, q0); q1 = fmaf(v, b.y, q1);
          q2 = fmaf(v, b.z, q2); q3 = fmaf(v, b.w, q3);
        }
      }
      Ks[tid & 127] = make_float4(CEXP*k0, CEXP*k1, CEXP*k2, CEXP*k3);
    } else {
#pragma unroll
      for (int cc = 0; cc < 16; ++cc) {
#pragma unroll
        for (int u = 0; u < 4; ++u) {
          float v = (u==0)?xv[cc].x:(u==1)?xv[cc].y:(u==2)?xv[cc].z:xv[cc].w;
          float4 b = fw[64 + cc*4+u];
          q0 = fmaf(v, b.x, q0); q1 = fmaf(v, b.y, q1);
          q2 = fmaf(v, b.z, q2); q3 = fmaf(v, b.w, q3);
        }
      }
    }
    Qs[QIDX(tid)] = make_float4(q0, q1, q2, q3);
  }
  __syncthreads();

  // ---- phase 2: ONLINE rowstats + in-wave shfl merge ----
  // thread = (quad = tid>>4 -> rows quad*4..+3, slice = tid&15 -> 32 j).
  // A row's 16 slice-partials live in 16 consecutive lanes of ONE wave ->
  // merge via 4 shfl_xor steps in registers. No Pp LDS, no merge barrier.
  {
    const int quad  = tid >> 4;
    const int slice = tid & 15;
    const float4 k0 = Ks[quad*4+0], k1 = Ks[quad*4+1];
    const float4 k2 = Ks[quad*4+2], k3 = Ks[quad*4+3];
    const float4* qb = &Qs[slice * 33];        // QIDX(slice*32) = slice*33

    float m0=-INFINITY, m1=-INFINITY, m2=-INFINITY, m3=-INFINITY;
    float l0=0.f, l1=0.f, l2=0.f, l3=0.f;
#pragma unroll
    for (int c = 0; c < 32; c += 8) {
      float4 qv0 = qb[c+0], qv1 = qb[c+1], qv2 = qb[c+2], qv3 = qb[c+3];
      float4 qv4 = qb[c+4], qv5 = qb[c+5], qv6 = qb[c+6], qv7 = qb[c+7];
#define ROW_ONLINE(KR, MR, LR)                                                 \
      {                                                                        \
        float d0 = DOT4(KR, qv0), d1 = DOT4(KR, qv1);                          \
        float d2 = DOT4(KR, qv2), d3 = DOT4(KR, qv3);                          \
        float d4 = DOT4(KR, qv4), d5 = DOT4(KR, qv5);                          \
        float d6 = DOT4(KR, qv6), d7 = DOT4(KR, qv7);                          \
        float cm = fmaxf(fmaxf(fmaxf(d0,d1), fmaxf(d2,d3)),                    \
                         fmaxf(fmaxf(d4,d5), fmaxf(d6,d7)));                   \
        if (cm > MR) { LR *= EXP2(MR - cm); MR = cm; }                         \
        LR += ((EXP2(d0-MR) + EXP2(d1-MR)) + (EXP2(d2-MR) + EXP2(d3-MR)))      \
            + ((EXP2(d4-MR) + EXP2(d5-MR)) + (EXP2(d6-MR) + EXP2(d7-MR)));     \
      }
      ROW_ONLINE(k0, m0, l0)
      ROW_ONLINE(k1, m1, l1)
      ROW_ONLINE(k2, m2, l2)
      ROW_ONLINE(k3, m3, l3)
#undef ROW_ONLINE
    }
    // merge 16 slice-partials per row across lanes (exact max, scaled sums)
#pragma unroll
    for (int off = 1; off <= 8; off <<= 1) {
#define MERGE(MR, LR)                                                          \
      {                                                                        \
        float om = __shfl_xor(MR, off);                                        \
        float ol = __shfl_xor(LR, off);                                        \
        float nm = fmaxf(MR, om);                                              \
        LR = fmaf(LR, EXP2(MR - nm), ol * EXP2(om - nm));                      \
        MR = nm;                                                               \
      }
      MERGE(m0, l0)
      MERGE(m1, l1)
      MERGE(m2, l2)
      MERGE(m3, l3)
#undef MERGE
    }
    if (slice == 0) {
      *reinterpret_cast<float4*>(&Cs[quad*4]) = make_float4(
          m0 + LOG2F(l0), m1 + LOG2F(l1), m2 + LOG2F(l2), m3 + LOG2F(l3));
    }
  }
  __syncthreads();

  // ---- phase 3: colsum, register-tiled (R10/R12 proven; padded Qs reads) ----
  {
    const int cq = tid & 127;
    const int rs = tid >> 7;
    const float4 q0 = Qs[QIDX(cq*4+0)], q1 = Qs[QIDX(cq*4+1)];
    const float4 q2 = Qs[QIDX(cq*4+2)], q3 = Qs[QIDX(cq*4+3)];
    const float4* kb = &Ks[rs << 5];
    const float4* cb = reinterpret_cast<const float4*>(&Cs[rs << 5]);

    float a0=0.f, a1=0.f, a2=0.f, a3=0.f;
#pragma unroll 2
    for (int ii = 0; ii < 8; ++ii) {
      float4 cc = cb[ii];
      float4 ka = kb[ii*4+0], kb_ = kb[ii*4+1], kc = kb[ii*4+2], kd = kb[ii*4+3];
      a0 += EXP2(DOT4A(q0, ka, -cc.x));  a1 += EXP2(DOT4A(q1, ka, -cc.x));
      a2 += EXP2(DOT4A(q2, ka, -cc.x));  a3 += EXP2(DOT4A(q3, ka, -cc.x));
      a0 += EXP2(DOT4A(q0, kb_, -cc.y)); a1 += EXP2(DOT4A(q1, kb_, -cc.y));
      a2 += EXP2(DOT4A(q2, kb_, -cc.y)); a3 += EXP2(DOT4A(q3, kb_, -cc.y));
      a0 += EXP2(DOT4A(q0, kc, -cc.z));  a1 += EXP2(DOT4A(q1, kc, -cc.z));
      a2 += EXP2(DOT4A(q2, kc, -cc.z));  a3 += EXP2(DOT4A(q3, kc, -cc.z));
      a0 += EXP2(DOT4A(q0, kd, -cc.w));  a1 += EXP2(DOT4A(q1, kd, -cc.w));
      a2 += EXP2(DOT4A(q2, kd, -cc.w));  a3 += EXP2(DOT4A(q3, kd, -cc.w));
    }
    reinterpret_cast<float4*>(apart + ((size_t)(tile*4 + s) * 4 + rs) * kN)[cq] =
        make_float4(a0, a1, a2, a3);
  }
}

// ============ KB: sum 16 partials + top-12; grid 128, block 64 ============
__global__ __launch_bounds__(64) void topk_kernel(
    const float* __restrict__ apart, int* __restrict__ out)
{
  const int lane = threadIdx.x;
  const int bt   = blockIdx.x;
  const float* P = apart + (size_t)bt * 16 * kN;

  float v[8];
  {
    float4 acc0 = make_float4(0.f,0.f,0.f,0.f);
    float4 acc1 = make_float4(0.f,0.f,0.f,0.f);
#pragma unroll
    for (int sl = 0; sl < 16; ++sl) {
      const float4* Ps = reinterpret_cast<const float4*>(P + sl * kN);
      float4 u0 = Ps[lane*2], u1 = Ps[lane*2+1];
      acc0.x += u0.x; acc0.y += u0.y; acc0.z += u0.z; acc0.w += u0.w;
      acc1.x += u1.x; acc1.y += u1.y; acc1.z += u1.z; acc1.w += u1.w;
    }
    v[0]=acc0.x; v[1]=acc0.y; v[2]=acc0.z; v[3]=acc0.w;
    v[4]=acc1.x; v[5]=acc1.y; v[6]=acc1.z; v[7]=acc1.w;
  }

  for (int rnd = 0; rnd < kTopK; ++rnd) {
    float bv = v[0];
    int   bi = lane * 8;
#pragma unroll
    for (int r = 1; r < 8; ++r) {
      if (v[r] > bv) { bv = v[r]; bi = lane * 8 + r; }
    }
#pragma unroll
    for (int off = 32; off >= 1; off >>= 1) {
      float ov = __shfl_xor(bv, off);
      int   oi = __shfl_xor(bi, off);
      if (ov > bv || (ov == bv && oi < bi)) { bv = ov; bi = oi; }
    }
    if (lane == 0) out[bt * kTopK + rnd] = bi;
#pragma unroll
    for (int r = 0; r < 8; ++r) {
      if (lane * 8 + r == bi) v[r] = -INFINITY;
    }
  }
}

// ============ fallback: round-1 single kernel (unexpected shape / tiny ws) ============
__global__ __launch_bounds__(512, 1) void sparse_attn_topk_fallback(
    const float* __restrict__ x, const float* __restrict__ flat, int* __restrict__ out)
{
  __shared__ float4 wk4[kDIn];
  __shared__ float4 wq4[kDIn];
  __shared__ float4 Ks[kN];
  __shared__ float4 Qs[kN];
  __shared__ float  Ms[kN];
  __shared__ float  Rl[kN];
  __shared__ float  As[kN];

  const int tid = threadIdx.x;
  const int bt  = blockIdx.x;

  if (tid < 64)       wk4[tid]      = reinterpret_cast<const float4*>(flat)[tid];
  else if (tid < 128) wq4[tid - 64] = reinterpret_cast<const float4*>(flat)[tid];
  __syncthreads();

  const float* xr = x + ((size_t)bt * kN + tid) * kDIn;
  float k0=0.f,k1=0.f,k2=0.f,k3=0.f, q0=0.f,q1=0.f,q2=0.f,q3=0.f;
#pragma unroll
  for (int c = 0; c < kDIn; ++c) {
    float xv = xr[c];
    float4 a = wk4[c];
    float4 b = wq4[c];
    k0 = fmaf(xv, a.x, k0); k1 = fmaf(xv, a.y, k1);
    k2 = fmaf(xv, a.z, k2); k3 = fmaf(xv, a.w, k3);
    q0 = fmaf(xv, b.x, q0); q1 = fmaf(xv, b.y, q1);
    q2 = fmaf(xv, b.z, q2); q3 = fmaf(xv, b.w, q3);
  }
  Ks[tid] = make_float4(k0, k1, k2, k3);
  Qs[tid] = make_float4(q0, q1, q2, q3);
  __syncthreads();

  float m = -INFINITY;
#pragma unroll 8
  for (int j = 0; j < kN; ++j) {
    float4 qj = Qs[j];
    float h = fmaf(k0, qj.x, fmaf(k1, qj.y, fmaf(k2, qj.z, k3 * qj.w)));
    m = fmaxf(m, h);
  }
  float l = 0.f;
#pragma unroll 8
  for (int j = 0; j < kN; ++j) {
    float4 qj = Qs[j];
    float h = fmaf(k0, qj.x, fmaf(k1, qj.y, fmaf(k2, qj.z, k3 * qj.w)));
    l += exp2f(CEXP * (h - m));
  }
  Ms[tid] = m;
  Rl[tid] = 1.0f / l;
  __syncthreads();

  float acc = 0.f;
#pragma unroll 8
  for (int i = 0; i < kN; ++i) {
    float4 ki = Ks[i];
    float h = fmaf(q0, ki.x, fmaf(q1, ki.y, fmaf(q2, ki.z, q3 * ki.w)));
    acc += exp2f(CEXP * (h - Ms[i])) * Rl[i];
  }
  As[tid] = acc;
  __syncthreads();

  if (tid < 64) {
    float v[8];
#pragma unroll
    for (int r = 0; r < 8; ++r) v[r] = As[tid * 8 + r];
    for (int rnd = 0; rnd < kTopK; ++rnd) {
      float bv = v[0];
      int   bi = tid * 8;
#pragma unroll
      for (int r = 1; r < 8; ++r)
        if (v[r] > bv) { bv = v[r]; bi = tid * 8 + r; }
#pragma unroll
      for (int off = 32; off >= 1; off >>= 1) {
        float ov = __shfl_xor(bv, off);
        int   oi = __shfl_xor(bi, off);
        if (ov > bv || (ov == bv && oi < bi)) { bv = ov; bi = oi; }
      }
      if (tid == 0) out[bt * kTopK + rnd] = bi;
#pragma unroll
      for (int r = 0; r < 8; ++r)
        if (tid * 8 + r == bi) v[r] = -INFINITY;
    }
  }
}

extern "C" void kernel_launch(void* const* d_in, const int* in_sizes, int n_in,
                              void* d_out, int out_size, void* d_ws, size_t ws_size,
                              hipStream_t stream) {
  const float* x    = (const float*)d_in[0];
  const float* flat = (const float*)d_in[1];
  int* out = (int*)d_out;
  const int n_bt = in_sizes[0] / (kN * kDIn);

  if (n_bt != kNBt || ws_size < kWsFloats * sizeof(float)) {
    sparse_attn_topk_fallback<<<n_bt, kN, 0, stream>>>(x, flat, out);
    return;
  }
  float* apart = (float*)d_ws;
  fused_attn_kernel<<<kNBt * kS, 512, 0, stream>>>(x, flat, apart);
  topk_kernel      <<<kNBt,       64, 0, stream>>>(apart, out);
}

// Round 16
// 36.055 us; speedup vs baseline: 3.1329x; 1.0358x over previous
//
#include <hip/hip_runtime.h>
#include <math.h>

// x: (8,16,512,64) fp32; flat = [wk | wq], each (64,4). Output: int32 top-12 idx.
constexpr int kDIn  = 64;
constexpr int kN    = 512;
constexpr int kTopK = 12;
constexpr int kNBt  = 128;          // 8*16
constexpr int kS    = 4;            // row-slices per tile
constexpr int kRows = kN / kS;      // 128 rows per block
// exp(SCALE*h) = exp2(CEXP*h); SCALE = 0.125; CEXP = SCALE*log2(e)
#define CEXP 0.18033688f
#define EXP2(v) __builtin_amdgcn_exp2f(v)
#define LOG2F(v) __builtin_amdgcn_logf(v)       // v_log_f32 = log base 2
// NUMERIC INVARIANT (R3/R5): every exp2 argument <= 0. Online rowstats keeps a
// running EXACT max at chunk granularity: rescale factor <= 1, slice l in
// [1,512]. No denormal, no inf, immune to FTZ.
// SYNC BUDGET (R11/R14): grid.sync()/__threadfence() cost 70-90us (cross-XCD
// L2 writeback) -- two-kernel pipeline is cheaper.
// LDS BUDGET (R9/R11/R16): ds_read_b128 ~12cyc issue, ~120cyc latency; batch
// reads 10-16 deep per waitcnt so latency amortizes. Weights stay in SGPRs.

#define DOT4(k, q)        fmaf((k).x,(q).x, fmaf((k).y,(q).y, fmaf((k).z,(q).z, (k).w*(q).w)))
#define DOT4A(k, q, add)  fmaf((k).x,(q).x, fmaf((k).y,(q).y, fmaf((k).z,(q).z, fmaf((k).w,(q).w,(add)))))

// ws: apart [128 tiles][16 slices][512 cols] floats = 4 MB
constexpr size_t kWsFloats = (size_t)kNBt * 16 * kN;

// ============ KA: fused projection + online rowstats + colsum ============
// grid 512, block 512, 2 blocks/CU. XCD swizzle keeps 4 same-tile blocks on one
// XCD (x tile L2-resident).
__global__ __launch_bounds__(512, 4) void fused_attn_kernel(
    const float* __restrict__ x, const float* __restrict__ flat,
    float* __restrict__ apart)
{
  __shared__ float4 Qs[kN];                    // unscaled Q (8 KB)
  __shared__ float4 Ks[kRows];                 // CEXP-scaled K slice (2 KB)
  __shared__ float2 Pp[16 * kRows];            // (m,l) per (j-slice,row) (16 KB)
  __shared__ __align__(16) float Cs[kRows];    // c_i = m_i + log2(l_i)

  const int tid  = threadIdx.x;
  const int p    = blockIdx.x;
  const int xcd  = p & 7;
  const int s    = (p >> 3) & 3;
  const int tile = ((p >> 5) << 3) | xcd;

  // ---- phase 1: thread t projects row t; 16 x-loads prefetched; weights via
  // uniform s_load (SGPR operands), zero LDS traffic. (R12/R13 proven)
  {
    const float4* fw  = reinterpret_cast<const float4*>(flat);   // [128] uniform
    const float4* xr4 = reinterpret_cast<const float4*>(x + ((size_t)tile * kN + tid) * kDIn);
    float4 xv[16];
#pragma unroll
    for (int i = 0; i < 16; ++i) xv[i] = xr4[i];

    float q0=0.f,q1=0.f,q2=0.f,q3=0.f;
    if ((tid >> 7) == s) {                     // wave-uniform branch
      float k0=0.f,k1=0.f,k2=0.f,k3=0.f;
#pragma unroll
      for (int cc = 0; cc < 16; ++cc) {
#pragma unroll
        for (int u = 0; u < 4; ++u) {
          float v = (u==0)?xv[cc].x:(u==1)?xv[cc].y:(u==2)?xv[cc].z:xv[cc].w;
          float4 a = fw[cc*4+u];
          float4 b = fw[64 + cc*4+u];
          k0 = fmaf(v, a.x, k0); k1 = fmaf(v, a.y, k1);
          k2 = fmaf(v, a.z, k2); k3 = fmaf(v, a.w, k3);
          q0 = fmaf(v, b.x, q0); q1 = fmaf(v, b.y, q1);
          q2 = fmaf(v, b.z, q2); q3 = fmaf(v, b.w, q3);
        }
      }
      Ks[tid & 127] = make_float4(CEXP*k0, CEXP*k1, CEXP*k2, CEXP*k3);
    } else {
#pragma unroll
      for (int cc = 0; cc < 16; ++cc) {
#pragma unroll
        for (int u = 0; u < 4; ++u) {
          float v = (u==0)?xv[cc].x:(u==1)?xv[cc].y:(u==2)?xv[cc].z:xv[cc].w;
          float4 b = fw[64 + cc*4+u];
          q0 = fmaf(v, b.x, q0); q1 = fmaf(v, b.y, q1);
          q2 = fmaf(v, b.z, q2); q3 = fmaf(v, b.w, q3);
        }
      }
    }
    Qs[tid] = make_float4(q0, q1, q2, q3);
  }
  __syncthreads();

  // ---- phase 2: ONLINE rowstats, register-tiled, 16-deep LDS batching ----
  // thread = (row-quad = tid&31 -> rows quad*4..+3, j-slice = tid>>5 -> 32 j).
  {
    const int quad  = tid & 31;
    const int slice = tid >> 5;
    const float4 k0 = Ks[quad*4+0], k1 = Ks[quad*4+1];
    const float4 k2 = Ks[quad*4+2], k3 = Ks[quad*4+3];
    const float4* qb = &Qs[slice << 5];

    float m0=-INFINITY, m1=-INFINITY, m2=-INFINITY, m3=-INFINITY;
    float l0=0.f, l1=0.f, l2=0.f, l3=0.f;
#pragma unroll
    for (int c = 0; c < 32; c += 16) {
      float4 qv[16];
#pragma unroll
      for (int i = 0; i < 16; ++i) qv[i] = qb[c + i];   // 16 reads in flight

#pragma unroll
      for (int h = 0; h < 16; h += 8) {
        float4 qv0 = qv[h+0], qv1 = qv[h+1], qv2 = qv[h+2], qv3 = qv[h+3];
        float4 qv4 = qv[h+4], qv5 = qv[h+5], qv6 = qv[h+6], qv7 = qv[h+7];
#define ROW_ONLINE(KR, MR, LR)                                                 \
        {                                                                      \
          float d0 = DOT4(KR, qv0), d1 = DOT4(KR, qv1);                        \
          float d2 = DOT4(KR, qv2), d3 = DOT4(KR, qv3);                        \
          float d4 = DOT4(KR, qv4), d5 = DOT4(KR, qv5);                        \
          float d6 = DOT4(KR, qv6), d7 = DOT4(KR, qv7);                        \
          float cm = fmaxf(fmaxf(fmaxf(d0,d1), fmaxf(d2,d3)),                  \
                           fmaxf(fmaxf(d4,d5), fmaxf(d6,d7)));                 \
          if (cm > MR) { LR *= EXP2(MR - cm); MR = cm; }                       \
          LR += ((EXP2(d0-MR) + EXP2(d1-MR)) + (EXP2(d2-MR) + EXP2(d3-MR)))    \
              + ((EXP2(d4-MR) + EXP2(d5-MR)) + (EXP2(d6-MR) + EXP2(d7-MR)));   \
        }
        ROW_ONLINE(k0, m0, l0)
        ROW_ONLINE(k1, m1, l1)
        ROW_ONLINE(k2, m2, l2)
        ROW_ONLINE(k3, m3, l3)
#undef ROW_ONLINE
      }
    }
    float4* pp4 = reinterpret_cast<float4*>(&Pp[slice * kRows + quad*4]);
    pp4[0] = make_float4(m0, l0, m1, l1);
    pp4[1] = make_float4(m2, l2, m3, l3);
  }
  __syncthreads();

  // ---- merge 16 j-slice partials per row (exact max, scaled sums) ----
  if (tid < kRows) {
    float m = -INFINITY;
    float2 pr[16];
#pragma unroll
    for (int sl = 0; sl < 16; ++sl) {
      pr[sl] = Pp[sl * kRows + tid];
      m = fmaxf(m, pr[sl].x);
    }
    float l = 0.f;
#pragma unroll
    for (int sl = 0; sl < 16; ++sl) l += pr[sl].y * EXP2(pr[sl].x - m);
    Cs[tid] = m + LOG2F(l);            // l in [1,512]
  }
  __syncthreads();

  // ---- phase 3: colsum, register-tiled, 10-deep LDS batching ----
  {
    const int cq = tid & 127;
    const int rs = tid >> 7;
    const float4 q0 = Qs[cq*4+0], q1 = Qs[cq*4+1];
    const float4 q2 = Qs[cq*4+2], q3 = Qs[cq*4+3];
    const float4* kb = &Ks[rs << 5];
    const float4* cb = reinterpret_cast<const float4*>(&Cs[rs << 5]);

    float a0=0.f, a1=0.f, a2=0.f, a3=0.f;
#pragma unroll
    for (int ii = 0; ii < 8; ii += 2) {
      float4 cc0 = cb[ii], cc1 = cb[ii+1];
      float4 kv[8];
#pragma unroll
      for (int i = 0; i < 8; ++i) kv[i] = kb[ii*4 + i];  // 10 reads in flight

#define COL_BLK(KA_, KB_, KC_, KD_, CC)                                        \
      {                                                                        \
        a0 += EXP2(DOT4A(q0, KA_, -(CC).x));  a1 += EXP2(DOT4A(q1, KA_, -(CC).x)); \
        a2 += EXP2(DOT4A(q2, KA_, -(CC).x));  a3 += EXP2(DOT4A(q3, KA_, -(CC).x)); \
        a0 += EXP2(DOT4A(q0, KB_, -(CC).y));  a1 += EXP2(DOT4A(q1, KB_, -(CC).y)); \
        a2 += EXP2(DOT4A(q2, KB_, -(CC).y));  a3 += EXP2(DOT4A(q3, KB_, -(CC).y)); \
        a0 += EXP2(DOT4A(q0, KC_, -(CC).z));  a1 += EXP2(DOT4A(q1, KC_, -(CC).z)); \
        a2 += EXP2(DOT4A(q2, KC_, -(CC).z));  a3 += EXP2(DOT4A(q3, KC_, -(CC).z)); \
        a0 += EXP2(DOT4A(q0, KD_, -(CC).w));  a1 += EXP2(DOT4A(q1, KD_, -(CC).w)); \
        a2 += EXP2(DOT4A(q2, KD_, -(CC).w));  a3 += EXP2(DOT4A(q3, KD_, -(CC).w)); \
      }
      COL_BLK(kv[0], kv[1], kv[2], kv[3], cc0)
      COL_BLK(kv[4], kv[5], kv[6], kv[7], cc1)
#undef COL_BLK
    }
    reinterpret_cast<float4*>(apart + ((size_t)(tile*4 + s) * 4 + rs) * kN)[cq] =
        make_float4(a0, a1, a2, a3);
  }
}

// ============ KB: sum 16 partials + top-12; grid 128, block 64 ============
__global__ __launch_bounds__(64) void topk_kernel(
    const float* __restrict__ apart, int* __restrict__ out)
{
  const int lane = threadIdx.x;
  const int bt   = blockIdx.x;
  const float* P = apart + (size_t)bt * 16 * kN;

  float v[8];
  {
    float4 acc0 = make_float4(0.f,0.f,0.f,0.f);
    float4 acc1 = make_float4(0.f,0.f,0.f,0.f);
#pragma unroll
    for (int sl = 0; sl < 16; ++sl) {
      const float4* Ps = reinterpret_cast<const float4*>(P + sl * kN);
      float4 u0 = Ps[lane*2], u1 = Ps[lane*2+1];
      acc0.x += u0.x; acc0.y += u0.y; acc0.z += u0.z; acc0.w += u0.w;
      acc1.x += u1.x; acc1.y += u1.y; acc1.z += u1.z; acc1.w += u1.w;
    }
    v[0]=acc0.x; v[1]=acc0.y; v[2]=acc0.z; v[3]=acc0.w;
    v[4]=acc1.x; v[5]=acc1.y; v[6]=acc1.z; v[7]=acc1.w;
  }

  for (int rnd = 0; rnd < kTopK; ++rnd) {
    float bv = v[0];
    int   bi = lane * 8;
#pragma unroll
    for (int r = 1; r < 8; ++r) {
      if (v[r] > bv) { bv = v[r]; bi = lane * 8 + r; }
    }
#pragma unroll
    for (int off = 32; off >= 1; off >>= 1) {
      float ov = __shfl_xor(bv, off);
      int   oi = __shfl_xor(bi, off);
      if (ov > bv || (ov == bv && oi < bi)) { bv = ov; bi = oi; }
    }
    if (lane == 0) out[bt * kTopK + rnd] = bi;
#pragma unroll
    for (int r = 0; r < 8; ++r) {
      if (lane * 8 + r == bi) v[r] = -INFINITY;
    }
  }
}

// ============ fallback: round-1 single kernel (unexpected shape / tiny ws) ============
__global__ __launch_bounds__(512, 1) void sparse_attn_topk_fallback(
    const float* __restrict__ x, const float* __restrict__ flat, int* __restrict__ out)
{
  __shared__ float4 wk4[kDIn];
  __shared__ float4 wq4[kDIn];
  __shared__ float4 Ks[kN];
  __shared__ float4 Qs[kN];
  __shared__ float  Ms[kN];
  __shared__ float  Rl[kN];
  __shared__ float  As[kN];

  const int tid = threadIdx.x;
  const int bt  = blockIdx.x;

  if (tid < 64)       wk4[tid]      = reinterpret_cast<const float4*>(flat)[tid];
  else if (tid < 128) wq4[tid - 64] = reinterpret_cast<const float4*>(flat)[tid];
  __syncthreads();

  const float* xr = x + ((size_t)bt * kN + tid) * kDIn;
  float k0=0.f,k1=0.f,k2=0.f,k3=0.f, q0=0.f,q1=0.f,q2=0.f,q3=0.f;
#pragma unroll
  for (int c = 0; c < kDIn; ++c) {
    float xv = xr[c];
    float4 a = wk4[c];
    float4 b = wq4[c];
    k0 = fmaf(xv, a.x, k0); k1 = fmaf(xv, a.y, k1);
    k2 = fmaf(xv, a.z, k2); k3 = fmaf(xv, a.w, k3);
    q0 = fmaf(xv, b.x, q0); q1 = fmaf(xv, b.y, q1);
    q2 = fmaf(xv, b.z, q2); q3 = fmaf(xv, b.w, q3);
  }
  Ks[tid] = make_float4(k0, k1, k2, k3);
  Qs[tid] = make_float4(q0, q1, q2, q3);
  __syncthreads();

  float m = -INFINITY;
#pragma unroll 8
  for (int j = 0; j < kN; ++j) {
    float4 qj = Qs[j];
    float h = fmaf(k0, qj.x, fmaf(k1, qj.y, fmaf(k2, qj.z, k3 * qj.w)));
    m = fmaxf(m, h);
  }
  float l = 0.f;
#pragma unroll 8
  for (int j = 0; j < kN; ++j) {
    float4 qj = Qs[j];
    float h = fmaf(k0, qj.x, fmaf(k1, qj.y, fmaf(k2, qj.z, k3 * qj.w)));
    l += exp2f(CEXP * (h - m));
  }
  Ms[tid] = m;
  Rl[tid] = 1.0f / l;
  __syncthreads();

  float acc = 0.f;
#pragma unroll 8
  for (int i = 0; i < kN; ++i) {
    float4 ki = Ks[i];
    float h = fmaf(q0, ki.x, fmaf(q1, ki.y, fmaf(q2, ki.z, q3 * ki.w)));
    acc += exp2f(CEXP * (h - Ms[i])) * Rl[i];
  }
  As[tid] = acc;
  __syncthreads();

  if (tid < 64) {
    float v[8];
#pragma unroll
    for (int r = 0; r < 8; ++r) v[r] = As[tid * 8 + r];
    for (int rnd = 0; rnd < kTopK; ++rnd) {
      float bv = v[0];
      int   bi = tid * 8;
#pragma unroll
      for (int r = 1; r < 8; ++r)
        if (v[r] > bv) { bv = v[r]; bi = tid * 8 + r; }
#pragma unroll
      for (int off = 32; off >= 1; off >>= 1) {
        float ov = __shfl_xor(bv, off);
        int   oi = __shfl_xor(bi, off);
        if (ov > bv || (ov == bv && oi < bi)) { bv = ov; bi = oi; }
      }
      if (tid == 0) out[bt * kTopK + rnd] = bi;
#pragma unroll
      for (int r = 0; r < 8; ++r)
        if (tid * 8 + r == bi) v[r] = -INFINITY;
    }
  }
}

extern "C" void kernel_launch(void* const* d_in, const int* in_sizes, int n_in,
                              void* d_out, int out_size, void* d_ws, size_t ws_size,
                              hipStream_t stream) {
  const float* x    = (const float*)d_in[0];
  const float* flat = (const float*)d_in[1];
  int* out = (int*)d_out;
  const int n_bt = in_sizes[0] / (kN * kDIn);

  if (n_bt != kNBt || ws_size < kWsFloats * sizeof(float)) {
    sparse_attn_topk_fallback<<<n_bt, kN, 0, stream>>>(x, flat, out);
    return;
  }
  float* apart = (float*)d_ws;
  fused_attn_kernel<<<kNBt * kS, 512, 0, stream>>>(x, flat, apart);
  topk_kernel      <<<kNBt,       64, 0, stream>>>(apart, out);
}

// Round 18
// 35.677 us; speedup vs baseline: 3.1661x; 1.0106x over previous
//
#include <hip/hip_runtime.h>
#include <math.h>

// x: (8,16,512,64) fp32; flat = [wk | wq], each (64,4). Output: int32 top-12 idx.
constexpr int kDIn  = 64;
constexpr int kN    = 512;
constexpr int kTopK = 12;
constexpr int kNBt  = 128;          // 8*16
constexpr int kS    = 4;            // row-slices per tile
constexpr int kRows = kN / kS;      // 128 rows per block
// exp(SCALE*h) = exp2(CEXP*h); SCALE = 0.125; CEXP = SCALE*log2(e)
#define CEXP 0.18033688f
#define EXP2(v) __builtin_amdgcn_exp2f(v)
#define LOG2F(v) __builtin_amdgcn_logf(v)       // v_log_f32 = log base 2
// NUMERIC INVARIANT (R3/R5/R17 — three failures triangulate it): every exp2
// argument must be <= 0 via an EXACT (running) row max. h = k.q has
// EXPONENTIAL tails (products of Gaussians): max |h'| over 33.5M samples is
// ~200 exp2-units, so NO fixed shift window exists (R17: inf at -64; R5:
// denormal-collapse at -128; R3: CS overshoot underflow). Online exact max:
// rescale factor <= 1, slice l in [1,512]. No denormal, no inf, FTZ-immune.
// SYNC BUDGET (R11/R14): grid.sync()/__threadfence() cost 70-90us (cross-XCD
// L2 writeback) -- two-kernel pipeline is cheaper.
// LDS BUDGET (R9/R11/R16): ds_read_b128 ~12cyc issue, ~120cyc latency; batch
// reads 10-16 deep per waitcnt. Weights stay in SGPRs (uniform s_load).

#define DOT4(k, q)        fmaf((k).x,(q).x, fmaf((k).y,(q).y, fmaf((k).z,(q).z, (k).w*(q).w)))
#define DOT4A(k, q, add)  fmaf((k).x,(q).x, fmaf((k).y,(q).y, fmaf((k).z,(q).z, fmaf((k).w,(q).w,(add)))))

// ws: apart [128 tiles][16 slices][512 cols] floats = 4 MB
constexpr size_t kWsFloats = (size_t)kNBt * 16 * kN;

// ============ KA: fused projection + online rowstats + colsum ============
// grid 512, block 512, 2 blocks/CU. XCD swizzle keeps 4 same-tile blocks on one
// XCD (x tile L2-resident).
__global__ __launch_bounds__(512, 4) void fused_attn_kernel(
    const float* __restrict__ x, const float* __restrict__ flat,
    float* __restrict__ apart)
{
  __shared__ float4 Qs[kN];                    // unscaled Q (8 KB)
  __shared__ float4 Ks[kRows];                 // CEXP-scaled K slice (2 KB)
  __shared__ float2 Pp[16 * kRows];            // (m,l) per (j-slice,row) (16 KB)
  __shared__ __align__(16) float Cs[kRows];    // c_i = m_i + log2(l_i)

  const int tid  = threadIdx.x;
  const int p    = blockIdx.x;
  const int xcd  = p & 7;
  const int s    = (p >> 3) & 3;
  const int tile = ((p >> 5) << 3) | xcd;

  // ---- phase 1: thread t projects row t; 16 x-loads prefetched; weights via
  // uniform s_load (SGPR operands), zero LDS traffic. (R12/R13 proven)
  {
    const float4* fw  = reinterpret_cast<const float4*>(flat);   // [128] uniform
    const float4* xr4 = reinterpret_cast<const float4*>(x + ((size_t)tile * kN + tid) * kDIn);
    float4 xv[16];
#pragma unroll
    for (int i = 0; i < 16; ++i) xv[i] = xr4[i];

    float q0=0.f,q1=0.f,q2=0.f,q3=0.f;
    if ((tid >> 7) == s) {                     // wave-uniform branch
      float k0=0.f,k1=0.f,k2=0.f,k3=0.f;
#pragma unroll
      for (int cc = 0; cc < 16; ++cc) {
#pragma unroll
        for (int u = 0; u < 4; ++u) {
          float v = (u==0)?xv[cc].x:(u==1)?xv[cc].y:(u==2)?xv[cc].z:xv[cc].w;
          float4 a = fw[cc*4+u];
          float4 b = fw[64 + cc*4+u];
          k0 = fmaf(v, a.x, k0); k1 = fmaf(v, a.y, k1);
          k2 = fmaf(v, a.z, k2); k3 = fmaf(v, a.w, k3);
          q0 = fmaf(v, b.x, q0); q1 = fmaf(v, b.y, q1);
          q2 = fmaf(v, b.z, q2); q3 = fmaf(v, b.w, q3);
        }
      }
      Ks[tid & 127] = make_float4(CEXP*k0, CEXP*k1, CEXP*k2, CEXP*k3);
    } else {
#pragma unroll
      for (int cc = 0; cc < 16; ++cc) {
#pragma unroll
        for (int u = 0; u < 4; ++u) {
          float v = (u==0)?xv[cc].x:(u==1)?xv[cc].y:(u==2)?xv[cc].z:xv[cc].w;
          float4 b = fw[64 + cc*4+u];
          q0 = fmaf(v, b.x, q0); q1 = fmaf(v, b.y, q1);
          q2 = fmaf(v, b.z, q2); q3 = fmaf(v, b.w, q3);
        }
      }
    }
    Qs[tid] = make_float4(q0, q1, q2, q3);
  }
  __syncthreads();

  // ---- phase 2: ONLINE rowstats, register-tiled, 16-deep LDS batching ----
  // thread = (row-quad = tid&31 -> rows quad*4..+3, j-slice = tid>>5 -> 32 j).
  // Rescale is UNCONDITIONAL (exp2(0)=1 exactly when max unchanged) -- removes
  // the per-lane divergent branch; numerics byte-identical to R16.
  {
    const int quad  = tid & 31;
    const int slice = tid >> 5;
    const float4 k0 = Ks[quad*4+0], k1 = Ks[quad*4+1];
    const float4 k2 = Ks[quad*4+2], k3 = Ks[quad*4+3];
    const float4* qb = &Qs[slice << 5];

    float m0=-INFINITY, m1=-INFINITY, m2=-INFINITY, m3=-INFINITY;
    float l0=0.f, l1=0.f, l2=0.f, l3=0.f;
#pragma unroll
    for (int c = 0; c < 32; c += 16) {
      float4 qv[16];
#pragma unroll
      for (int i = 0; i < 16; ++i) qv[i] = qb[c + i];   // 16 reads in flight

#pragma unroll
      for (int h = 0; h < 16; h += 8) {
        float4 qv0 = qv[h+0], qv1 = qv[h+1], qv2 = qv[h+2], qv3 = qv[h+3];
        float4 qv4 = qv[h+4], qv5 = qv[h+5], qv6 = qv[h+6], qv7 = qv[h+7];
#define ROW_ONLINE(KR, MR, LR)                                                 \
        {                                                                      \
          float d0 = DOT4(KR, qv0), d1 = DOT4(KR, qv1);                        \
          float d2 = DOT4(KR, qv2), d3 = DOT4(KR, qv3);                        \
          float d4 = DOT4(KR, qv4), d5 = DOT4(KR, qv5);                        \
          float d6 = DOT4(KR, qv6), d7 = DOT4(KR, qv7);                        \
          float cm = fmaxf(fmaxf(fmaxf(d0,d1), fmaxf(d2,d3)),                  \
                           fmaxf(fmaxf(d4,d5), fmaxf(d6,d7)));                 \
          float nm = fmaxf(MR, cm);                                            \
          LR *= EXP2(MR - nm);   /* ==1.0 exactly when max unchanged */        \
          MR = nm;                                                             \
          LR += ((EXP2(d0-MR) + EXP2(d1-MR)) + (EXP2(d2-MR) + EXP2(d3-MR)))    \
              + ((EXP2(d4-MR) + EXP2(d5-MR)) + (EXP2(d6-MR) + EXP2(d7-MR)));   \
        }
        ROW_ONLINE(k0, m0, l0)
        ROW_ONLINE(k1, m1, l1)
        ROW_ONLINE(k2, m2, l2)
        ROW_ONLINE(k3, m3, l3)
#undef ROW_ONLINE
      }
    }
    float4* pp4 = reinterpret_cast<float4*>(&Pp[slice * kRows + quad*4]);
    pp4[0] = make_float4(m0, l0, m1, l1);
    pp4[1] = make_float4(m2, l2, m3, l3);
  }
  __syncthreads();

  // ---- merge 16 j-slice partials per row (exact max, scaled sums) ----
  if (tid < kRows) {
    float m = -INFINITY;
    float2 pr[16];
#pragma unroll
    for (int sl = 0; sl < 16; ++sl) {
      pr[sl] = Pp[sl * kRows + tid];
      m = fmaxf(m, pr[sl].x);
    }
    float l = 0.f;
#pragma unroll
    for (int sl = 0; sl < 16; ++sl) l += pr[sl].y * EXP2(pr[sl].x - m);
    Cs[tid] = m + LOG2F(l);            // l in [1,512]
  }
  __syncthreads();

  // ---- phase 3: colsum, register-tiled, 10-deep LDS batching (R16 proven) ----
  {
    const int cq = tid & 127;
    const int rs = tid >> 7;
    const float4 q0 = Qs[cq*4+0], q1 = Qs[cq*4+1];
    const float4 q2 = Qs[cq*4+2], q3 = Qs[cq*4+3];
    const float4* kb = &Ks[rs << 5];
    const float4* cb = reinterpret_cast<const float4*>(&Cs[rs << 5]);

    float a0=0.f, a1=0.f, a2=0.f, a3=0.f;
#pragma unroll
    for (int ii = 0; ii < 8; ii += 2) {
      float4 cc0 = cb[ii], cc1 = cb[ii+1];
      float4 kv[8];
#pragma unroll
      for (int i = 0; i < 8; ++i) kv[i] = kb[ii*4 + i];  // 10 reads in flight

#define COL_BLK(KA_, KB_, KC_, KD_, CC)                                        \
      {                                                                        \
        a0 += EXP2(DOT4A(q0, KA_, -(CC).x));  a1 += EXP2(DOT4A(q1, KA_, -(CC).x)); \
        a2 += EXP2(DOT4A(q2, KA_, -(CC).x));  a3 += EXP2(DOT4A(q3, KA_, -(CC).x)); \
        a0 += EXP2(DOT4A(q0, KB_, -(CC).y));  a1 += EXP2(DOT4A(q1, KB_, -(CC).y)); \
        a2 += EXP2(DOT4A(q2, KB_, -(CC).y));  a3 += EXP2(DOT4A(q3, KB_, -(CC).y)); \
        a0 += EXP2(DOT4A(q0, KC_, -(CC).z));  a1 += EXP2(DOT4A(q1, KC_, -(CC).z)); \
        a2 += EXP2(DOT4A(q2, KC_, -(CC).z));  a3 += EXP2(DOT4A(q3, KC_, -(CC).z)); \
        a0 += EXP2(DOT4A(q0, KD_, -(CC).w));  a1 += EXP2(DOT4A(q1, KD_, -(CC).w)); \
        a2 += EXP2(DOT4A(q2, KD_, -(CC).w));  a3 += EXP2(DOT4A(q3, KD_, -(CC).w)); \
      }
      COL_BLK(kv[0], kv[1], kv[2], kv[3], cc0)
      COL_BLK(kv[4], kv[5], kv[6], kv[7], cc1)
#undef COL_BLK
    }
    reinterpret_cast<float4*>(apart + ((size_t)(tile*4 + s) * 4 + rs) * kN)[cq] =
        make_float4(a0, a1, a2, a3);
  }
}

// ============ KB: sum 16 partials + top-12; grid 128, block 64 ============
__global__ __launch_bounds__(64) void topk_kernel(
    const float* __restrict__ apart, int* __restrict__ out)
{
  const int lane = threadIdx.x;
  const int bt   = blockIdx.x;
  const float* P = apart + (size_t)bt * 16 * kN;

  float v[8];
  {
    float4 acc0 = make_float4(0.f,0.f,0.f,0.f);
    float4 acc1 = make_float4(0.f,0.f,0.f,0.f);
#pragma unroll
    for (int sl = 0; sl < 16; ++sl) {
      const float4* Ps = reinterpret_cast<const float4*>(P + sl * kN);
      float4 u0 = Ps[lane*2], u1 = Ps[lane*2+1];
      acc0.x += u0.x; acc0.y += u0.y; acc0.z += u0.z; acc0.w += u0.w;
      acc1.x += u1.x; acc1.y += u1.y; acc1.z += u1.z; acc1.w += u1.w;
    }
    v[0]=acc0.x; v[1]=acc0.y; v[2]=acc0.z; v[3]=acc0.w;
    v[4]=acc1.x; v[5]=acc1.y; v[6]=acc1.z; v[7]=acc1.w;
  }

  for (int rnd = 0; rnd < kTopK; ++rnd) {
    float bv = v[0];
    int   bi = lane * 8;
#pragma unroll
    for (int r = 1; r < 8; ++r) {
      if (v[r] > bv) { bv = v[r]; bi = lane * 8 + r; }
    }
#pragma unroll
    for (int off = 32; off >= 1; off >>= 1) {
      float ov = __shfl_xor(bv, off);
      int   oi = __shfl_xor(bi, off);
      if (ov > bv || (ov == bv && oi < bi)) { bv = ov; bi = oi; }
    }
    if (lane == 0) out[bt * kTopK + rnd] = bi;
#pragma unroll
    for (int r = 0; r < 8; ++r) {
      if (lane * 8 + r == bi) v[r] = -INFINITY;
    }
  }
}

// ============ fallback: round-1 single kernel (unexpected shape / tiny ws) ============
__global__ __launch_bounds__(512, 1) void sparse_attn_topk_fallback(
    const float* __restrict__ x, const float* __restrict__ flat, int* __restrict__ out)
{
  __shared__ float4 wk4[kDIn];
  __shared__ float4 wq4[kDIn];
  __shared__ float4 Ks[kN];
  __shared__ float4 Qs[kN];
  __shared__ float  Ms[kN];
  __shared__ float  Rl[kN];
  __shared__ float  As[kN];

  const int tid = threadIdx.x;
  const int bt  = blockIdx.x;

  if (tid < 64)       wk4[tid]      = reinterpret_cast<const float4*>(flat)[tid];
  else if (tid < 128) wq4[tid - 64] = reinterpret_cast<const float4*>(flat)[tid];
  __syncthreads();

  const float* xr = x + ((size_t)bt * kN + tid) * kDIn;
  float k0=0.f,k1=0.f,k2=0.f,k3=0.f, q0=0.f,q1=0.f,q2=0.f,q3=0.f;
#pragma unroll
  for (int c = 0; c < kDIn; ++c) {
    float xv = xr[c];
    float4 a = wk4[c];
    float4 b = wq4[c];
    k0 = fmaf(xv, a.x, k0); k1 = fmaf(xv, a.y, k1);
    k2 = fmaf(xv, a.z, k2); k3 = fmaf(xv, a.w, k3);
    q0 = fmaf(xv, b.x, q0); q1 = fmaf(xv, b.y, q1);
    q2 = fmaf(xv, b.z, q2); q3 = fmaf(xv, b.w, q3);
  }
  Ks[tid] = make_float4(k0, k1, k2, k3);
  Qs[tid] = make_float4(q0, q1, q2, q3);
  __syncthreads();

  float m = -INFINITY;
#pragma unroll 8
  for (int j = 0; j < kN; ++j) {
    float4 qj = Qs[j];
    float h = fmaf(k0, qj.x, fmaf(k1, qj.y, fmaf(k2, qj.z, k3 * qj.w)));
    m = fmaxf(m, h);
  }
  float l = 0.f;
#pragma unroll 8
  for (int j = 0; j < kN; ++j) {
    float4 qj = Qs[j];
    float h = fmaf(k0, qj.x, fmaf(k1, qj.y, fmaf(k2, qj.z, k3 * qj.w)));
    l += exp2f(CEXP * (h - m));
  }
  Ms[tid] = m;
  Rl[tid] = 1.0f / l;
  __syncthreads();

  float acc = 0.f;
#pragma unroll 8
  for (int i = 0; i < kN; ++i) {
    float4 ki = Ks[i];
    float h = fmaf(q0, ki.x, fmaf(q1, ki.y, fmaf(q2, ki.z, q3 * ki.w)));
    acc += exp2f(CEXP * (h - Ms[i])) * Rl[i];
  }
  As[tid] = acc;
  __syncthreads();

  if (tid < 64) {
    float v[8];
#pragma unroll
    for (int r = 0; r < 8; ++r) v[r] = As[tid * 8 + r];
    for (int rnd = 0; rnd < kTopK; ++rnd) {
      float bv = v[0];
      int   bi = tid * 8;
#pragma unroll
      for (int r = 1; r < 8; ++r)
        if (v[r] > bv) { bv = v[r]; bi = tid * 8 + r; }
#pragma unroll
      for (int off = 32; off >= 1; off >>= 1) {
        float ov = __shfl_xor(bv, off);
        int   oi = __shfl_xor(bi, off);
        if (ov > bv || (ov == bv && oi < bi)) { bv = ov; bi = oi; }
      }
      if (tid == 0) out[bt * kTopK + rnd] = bi;
#pragma unroll
      for (int r = 0; r < 8; ++r)
        if (tid * 8 + r == bi) v[r] = -INFINITY;
    }
  }
}

extern "C" void kernel_launch(void* const* d_in, const int* in_sizes, int n_in,
                              void* d_out, int out_size, void* d_ws, size_t ws_size,
                              hipStream_t stream) {
  const float* x    = (const float*)d_in[0];
  const float* flat = (const float*)d_in[1];
  int* out = (int*)d_out;
  const int n_bt = in_sizes[0] / (kN * kDIn);

  if (n_bt != kNBt || ws_size < kWsFloats * sizeof(float)) {
    sparse_attn_topk_fallback<<<n_bt, kN, 0, stream>>>(x, flat, out);
    return;
  }
  float* apart = (float*)d_ws;
  fused_attn_kernel<<<kNBt * kS, 512, 0, stream>>>(x, flat, apart);
  topk_kernel      <<<kNBt,       64, 0, stream>>>(apart, out);
}